// Round 1
// baseline (2461.609 us; speedup 1.0000x reference)
//
#include <hip/hip_runtime.h>
#include <cstdint>
#include <cstddef>

#define ND      128
#define NNODES  50000
#define NEDGES  640000
#define BNEPS   1e-5f

// ---------- float <-> order-preserving uint key (for atomicMax on floats) ----------
__device__ __forceinline__ unsigned fkey(float f) {
    unsigned u = __float_as_uint(f);
    return (u & 0x80000000u) ? ~u : (u | 0x80000000u);
}
__device__ __forceinline__ float funkey(unsigned k) {
    return (k & 0x80000000u) ? __uint_as_float(k & 0x7fffffffu) : __uint_as_float(~k);
}

// ---------- K1: per-edge attention logit + segment max ----------
__global__ __launch_bounds__(256) void attn_max_kernel(
    const float* __restrict__ nh, const float* __restrict__ eh,
    const int* __restrict__ ei, float* __restrict__ attn,
    unsigned* __restrict__ segmax) {
    int gid  = blockIdx.x * 256 + threadIdx.x;
    int e    = gid >> 6;
    int lane = threadIdx.x & 63;
    if (e >= NEDGES) return;
    int s = ei[e], d = ei[NEDGES + e];
    float2 sv = ((const float2*)(nh + (size_t)s * ND))[lane];
    float2 dv = ((const float2*)(nh + (size_t)d * ND))[lane];
    float2 ev = ((const float2*)(eh + (size_t)e * ND))[lane];
    float acc = (sv.x + ev.x) * dv.x + (sv.y + ev.y) * dv.y;
#pragma unroll
    for (int off = 32; off > 0; off >>= 1) acc += __shfl_down(acc, off, 64);
    if (lane == 0) {
        attn[e] = acc;
        atomicMax(&segmax[d], fkey(acc));
    }
}

// ---------- K2: ex = exp(attn - max), segment sum ----------
__global__ __launch_bounds__(256) void ex_sum_kernel(
    const int* __restrict__ ei, float* __restrict__ attn,
    const unsigned* __restrict__ segmax, float* __restrict__ segsum) {
    int e = blockIdx.x * 256 + threadIdx.x;
    if (e >= NEDGES) return;
    int d = ei[NEDGES + e];
    float m  = funkey(segmax[d]);
    float ex = __expf(attn[e] - m);
    attn[e]  = ex;  // reuse buffer as ex
    unsafeAtomicAdd(&segsum[d], ex);
}

// ---------- K3: scatter nz[dst] += alpha * nh[src] ----------
__global__ __launch_bounds__(256) void scatter_kernel(
    const float* __restrict__ nh, const int* __restrict__ ei,
    const float* __restrict__ ex, const float* __restrict__ segsum,
    float* __restrict__ nz) {
    int gid  = blockIdx.x * 256 + threadIdx.x;
    int e    = gid >> 6;
    int lane = threadIdx.x & 63;
    if (e >= NEDGES) return;
    int s = ei[e], d = ei[NEDGES + e];
    float alpha = ex[e] / segsum[d];
    float2 sv = ((const float2*)(nh + (size_t)s * ND))[lane];
    float* dst = nz + (size_t)d * ND + lane * 2;
    unsafeAtomicAdd(dst,     sv.x * alpha);
    unsafeAtomicAdd(dst + 1, sv.y * alpha);
}

// ---------- K4: fused-input GEMM  out = [relu](X' @ W + b) ----------
// MODE 0: X' = (1+eps)*nh  + nz            (node pre, row-indexed nz)
// MODE 1: X' = (1+eps)*eh  + nz[src]-nz[dst] (edge pre, gathered nz)
// MODE 2: X' = X                            (plain; supports in-place X==out)
template <int MODE>
__global__ __launch_bounds__(256) void mlp_gemm(
    const float* __restrict__ X, const float* __restrict__ W,
    const float* __restrict__ bias, float* __restrict__ out, int M, int do_relu,
    const float* __restrict__ eps, const float* __restrict__ nz,
    const int* __restrict__ ei) {
    __shared__ float As[64][ND + 1];   // +1 pad: A-reads hit consecutive banks
    __shared__ float Bs[16][ND];
    __shared__ int   sIdx[2][64];

    int tid  = threadIdx.x;
    int tx   = tid & 15;   // col group (8 cols each)
    int ty   = tid >> 4;   // row group (4 rows each)
    int row0 = blockIdx.x * 64;

    if (MODE == 1) {
        if (tid < 64) {
            int r = row0 + tid;
            if (r >= M) r = M - 1;
            sIdx[0][tid] = ei[r];
            sIdx[1][tid] = ei[NEDGES + r];
        }
        __syncthreads();
    }

    // stage full 64x128 A tile with the input transform applied
    for (int i = tid; i < 64 * 32; i += 256) {
        int r   = i >> 5;
        int c   = (i & 31) << 2;
        int row = row0 + r;
        float4 v = make_float4(0.f, 0.f, 0.f, 0.f);
        if (row < M) {
            float4 xv = *(const float4*)(X + (size_t)row * ND + c);
            if (MODE == 2) {
                v = xv;
            } else if (MODE == 0) {
                float4 e4 = *(const float4*)(eps + c);
                float4 zv = *(const float4*)(nz + (size_t)row * ND + c);
                v.x = (1.f + e4.x) * xv.x + zv.x;
                v.y = (1.f + e4.y) * xv.y + zv.y;
                v.z = (1.f + e4.z) * xv.z + zv.z;
                v.w = (1.f + e4.w) * xv.w + zv.w;
            } else {
                float4 e4 = *(const float4*)(eps + c);
                float4 zs = *(const float4*)(nz + (size_t)sIdx[0][r] * ND + c);
                float4 zd = *(const float4*)(nz + (size_t)sIdx[1][r] * ND + c);
                v.x = (1.f + e4.x) * xv.x + zs.x - zd.x;
                v.y = (1.f + e4.y) * xv.y + zs.y - zd.y;
                v.z = (1.f + e4.z) * xv.z + zs.z - zd.z;
                v.w = (1.f + e4.w) * xv.w + zs.w - zd.w;
            }
        }
        As[r][c] = v.x; As[r][c + 1] = v.y; As[r][c + 2] = v.z; As[r][c + 3] = v.w;
    }

    float acc[4][8];
#pragma unroll
    for (int i = 0; i < 4; ++i)
#pragma unroll
        for (int j = 0; j < 8; ++j) acc[i][j] = 0.f;

    for (int kt = 0; kt < ND; kt += 16) {
        __syncthreads();  // As ready (first iter) / prev Bs reads done
        for (int i = tid; i < 16 * 32; i += 256) {
            int kr = i >> 5;
            int c  = (i & 31) << 2;
            *(float4*)(&Bs[kr][c]) = *(const float4*)(W + (size_t)(kt + kr) * ND + c);
        }
        __syncthreads();
#pragma unroll
        for (int k = 0; k < 16; ++k) {
            float a0 = As[ty * 4 + 0][kt + k];
            float a1 = As[ty * 4 + 1][kt + k];
            float a2 = As[ty * 4 + 2][kt + k];
            float a3 = As[ty * 4 + 3][kt + k];
            float b[8];
            *(float4*)&b[0] = *(const float4*)(&Bs[k][tx * 8]);
            *(float4*)&b[4] = *(const float4*)(&Bs[k][tx * 8 + 4]);
#pragma unroll
            for (int j = 0; j < 8; ++j) {
                acc[0][j] += a0 * b[j];
                acc[1][j] += a1 * b[j];
                acc[2][j] += a2 * b[j];
                acc[3][j] += a3 * b[j];
            }
        }
    }

#pragma unroll
    for (int i = 0; i < 4; ++i) {
        int row = row0 + ty * 4 + i;
        if (row >= M) continue;
        int c = tx * 8;
        float o[8];
#pragma unroll
        for (int j = 0; j < 8; ++j) {
            o[j] = acc[i][j] + bias[c + j];
            if (do_relu) o[j] = fmaxf(o[j], 0.f);
        }
        *(float4*)(out + (size_t)row * ND + c)     = *(float4*)&o[0];
        *(float4*)(out + (size_t)row * ND + c + 4) = *(float4*)&o[4];
    }
}

// ---------- K5: BN column stats (sum, sumsq) ----------
__global__ __launch_bounds__(256) void bn_stats_kernel(
    const float* __restrict__ x, int M,
    float* __restrict__ sum, float* __restrict__ sumsq) {
    __shared__ float ls[256], ls2[256];
    int col  = threadIdx.x & 127;
    int half = threadIdx.x >> 7;
    float s = 0.f, s2 = 0.f;
    for (int r = blockIdx.x * 2 + half; r < M; r += gridDim.x * 2) {
        float v = x[(size_t)r * ND + col];
        s += v; s2 += v * v;
    }
    ls[threadIdx.x] = s; ls2[threadIdx.x] = s2;
    __syncthreads();
    if (threadIdx.x < 128) {
        s  = ls[threadIdx.x]  + ls[threadIdx.x + 128];
        s2 = ls2[threadIdx.x] + ls2[threadIdx.x + 128];
        unsafeAtomicAdd(&sum[col], s);
        unsafeAtomicAdd(&sumsq[col], s2);
    }
}

// ---------- K6: fold stats into (scale, shift) in place ----------
__global__ void bn_finalize_kernel(float* __restrict__ sum, float* __restrict__ sumsq,
                                   const float* __restrict__ g, const float* __restrict__ b,
                                   float M) {
    int c = threadIdx.x;
    float mean  = sum[c] / M;
    float var   = sumsq[c] / M - mean * mean;
    float scale = g[c] * rsqrtf(var + BNEPS);
    sum[c]   = scale;             // scale
    sumsq[c] = b[c] - mean * scale;  // shift
}

// ---------- K7: BN apply in place ----------
__global__ __launch_bounds__(256) void bn_apply_kernel(
    float* __restrict__ x, int M,
    const float* __restrict__ scale, const float* __restrict__ shift) {
    size_t total4 = (size_t)M * (ND / 4);
    for (size_t i = (size_t)blockIdx.x * 256 + threadIdx.x; i < total4;
         i += (size_t)gridDim.x * 256) {
        int c = ((int)(i & 31)) << 2;
        float4 v = ((const float4*)x)[i];
        v.x = v.x * scale[c]     + shift[c];
        v.y = v.y * scale[c + 1] + shift[c + 1];
        v.z = v.z * scale[c + 2] + shift[c + 2];
        v.w = v.w * scale[c + 3] + shift[c + 3];
        ((float4*)x)[i] = v;
    }
}

extern "C" void kernel_launch(void* const* d_in, const int* in_sizes, int n_in,
                              void* d_out, int out_size, void* d_ws, size_t ws_size,
                              hipStream_t stream) {
    const float* nh       = (const float*)d_in[0];
    const float* eh       = (const float*)d_in[1];
    const int*   ei       = (const int*)d_in[2];
    const float* nf_eps   = (const float*)d_in[3];
    const float* ef_eps   = (const float*)d_in[4];
    const float* nf_W1    = (const float*)d_in[5];
    const float* nf_b1    = (const float*)d_in[6];
    const float* nf_W2    = (const float*)d_in[7];
    const float* nf_b2    = (const float*)d_in[8];
    const float* ef_W1    = (const float*)d_in[9];
    const float* ef_b1    = (const float*)d_in[10];
    const float* ef_W2    = (const float*)d_in[11];
    const float* ef_b2    = (const float*)d_in[12];
    const float* nf_gamma = (const float*)d_in[13];
    const float* nf_beta  = (const float*)d_in[14];
    const float* ef_gamma = (const float*)d_in[15];
    const float* ef_beta  = (const float*)d_in[16];

    float* out_n = (float*)d_out;                          // [N,128]
    float* out_e = (float*)d_out + (size_t)NNODES * ND;    // [E,128]

    char* ws = (char*)d_ws;
    size_t off = 0;
    auto alloc = [&](size_t bytes) -> void* {
        void* p = ws + off;
        off = (off + bytes + 255) & ~(size_t)255;
        return p;
    };
    float*    attn    = (float*)alloc((size_t)NEDGES * 4);      // later: ex
    unsigned* segmax  = (unsigned*)alloc((size_t)NNODES * 4);
    float*    segsum  = (float*)alloc((size_t)NNODES * 4);
    float*    nz      = (float*)alloc((size_t)NNODES * ND * 4);
    float*    ssum_n  = (float*)alloc(ND * 4);
    float*    ssq_n   = (float*)alloc(ND * 4);
    float*    ssum_e  = (float*)alloc(ND * 4);
    float*    ssq_e   = (float*)alloc(ND * 4);

    hipMemsetAsync(segmax, 0, (size_t)NNODES * 4, stream);
    hipMemsetAsync(segsum, 0, (size_t)NNODES * 4, stream);
    hipMemsetAsync(nz,     0, (size_t)NNODES * ND * 4, stream);
    hipMemsetAsync(ssum_n, 0, ND * 4, stream);
    hipMemsetAsync(ssq_n,  0, ND * 4, stream);
    hipMemsetAsync(ssum_e, 0, ND * 4, stream);
    hipMemsetAsync(ssq_e,  0, ND * 4, stream);

    attn_max_kernel<<<NEDGES / 4, 256, 0, stream>>>(nh, eh, ei, attn, segmax);
    ex_sum_kernel<<<(NEDGES + 255) / 256, 256, 0, stream>>>(ei, attn, segmax, segsum);
    scatter_kernel<<<NEDGES / 4, 256, 0, stream>>>(nh, ei, attn, segsum, nz);

    // node MLP: hidden into out_n, then in-place second layer
    mlp_gemm<0><<<(NNODES + 63) / 64, 256, 0, stream>>>(nh, nf_W1, nf_b1, out_n, NNODES, 1,
                                                        nf_eps, nz, nullptr);
    mlp_gemm<2><<<(NNODES + 63) / 64, 256, 0, stream>>>(out_n, nf_W2, nf_b2, out_n, NNODES, 0,
                                                        nullptr, nullptr, nullptr);
    // edge MLP
    mlp_gemm<1><<<NEDGES / 64, 256, 0, stream>>>(eh, ef_W1, ef_b1, out_e, NEDGES, 1,
                                                 ef_eps, nz, ei);
    mlp_gemm<2><<<NEDGES / 64, 256, 0, stream>>>(out_e, ef_W2, ef_b2, out_e, NEDGES, 0,
                                                 nullptr, nullptr, nullptr);

    bn_stats_kernel<<<512, 256, 0, stream>>>(out_n, NNODES, ssum_n, ssq_n);
    bn_stats_kernel<<<512, 256, 0, stream>>>(out_e, NEDGES, ssum_e, ssq_e);
    bn_finalize_kernel<<<1, 128, 0, stream>>>(ssum_n, ssq_n, nf_gamma, nf_beta, (float)NNODES);
    bn_finalize_kernel<<<1, 128, 0, stream>>>(ssum_e, ssq_e, ef_gamma, ef_beta, (float)NEDGES);
    bn_apply_kernel<<<2048, 256, 0, stream>>>(out_n, NNODES, ssum_n, ssq_n);
    bn_apply_kernel<<<8192, 256, 0, stream>>>(out_e, NEDGES, ssum_e, ssq_e);
}